// Round 4
// baseline (294.072 us; speedup 1.0000x reference)
//
#include <hip/hip_runtime.h>
#include <math.h>

// out[m, n] = base[n] - pre_cls[n, idx[m]],  base[n] = sum_c softplus(pre_cls[n, c])
// M = N = 8192, C = 80.
// Strategy: D[c][n] = base[n] - pre_cls[n, c] (2.6 MB, L2-resident after prep),
// then out row m = contiguous copy of D row idx[m]. HBM-write-bound (~41 us floor).

#define CE_C 80

typedef float f32x4 __attribute__((ext_vector_type(4)));

__device__ __forceinline__ float softplus_f(float x) {
    // logaddexp(x, 0) = max(x,0) + log1p(exp(-|x|))
    return fmaxf(x, 0.0f) + log1pf(expf(-fabsf(x)));
}

// One thread per n. Writes D[c][n] coalesced across n.
__global__ void ce_prep(const float* __restrict__ pre, float* __restrict__ D, int N) {
    int n = blockIdx.x * blockDim.x + threadIdx.x;
    if (n >= N) return;
    const float* row = pre + (long)n * CE_C;
    float base = 0.0f;
#pragma unroll
    for (int c = 0; c < CE_C; c += 4) {
        f32x4 v = *reinterpret_cast<const f32x4*>(row + c);
        base += softplus_f(v.x);
        base += softplus_f(v.y);
        base += softplus_f(v.z);
        base += softplus_f(v.w);
    }
#pragma unroll 4
    for (int c = 0; c < CE_C; ++c) {
        D[(long)c * N + n] = base - row[c];  // row[c] re-read hits L1
    }
}

// One block per output row. NVEC = N/4 known at compile time: no bounds checks.
// Load all 8 vectors into registers (8 loads in flight), then store burst.
// Regular stores (nontemporal measured -9us in R3).
template <int NVEC>
__global__ void __launch_bounds__(256) ce_gather_t(const f32x4* __restrict__ D,
                                                   const int* __restrict__ idx,
                                                   f32x4* __restrict__ out) {
    constexpr int PER_THREAD = NVEC / 256;
    const int m = blockIdx.x;
    const int c = idx[m];                                   // uniform within block
    const f32x4* __restrict__ src = D + (long)c * NVEC;
    f32x4* __restrict__ dst = out + (long)m * NVEC;
    const int t = threadIdx.x;
    f32x4 v[PER_THREAD];
#pragma unroll
    for (int j = 0; j < PER_THREAD; ++j) v[j] = src[j * 256 + t];
#pragma unroll
    for (int j = 0; j < PER_THREAD; ++j) dst[j * 256 + t] = v[j];
}

// Generic fallback (any N divisible by 4).
__global__ void __launch_bounds__(256) ce_gather(const float* __restrict__ D,
                                                 const int* __restrict__ idx,
                                                 float* __restrict__ out, int N) {
    const int m = blockIdx.x;
    const int c = idx[m];
    const f32x4* __restrict__ src = reinterpret_cast<const f32x4*>(D + (long)c * N);
    f32x4* __restrict__ dst = reinterpret_cast<f32x4*>(out + (long)m * N);
    const int nvec = N >> 2;
    for (int i = threadIdx.x; i < nvec; i += 256) dst[i] = src[i];
}

// ---- fallback path (workspace too small for D) ----
__global__ void ce_base(const float* __restrict__ pre, float* __restrict__ base, int N) {
    int n = blockIdx.x * blockDim.x + threadIdx.x;
    if (n >= N) return;
    const float* row = pre + (long)n * CE_C;
    float b = 0.0f;
#pragma unroll
    for (int c = 0; c < CE_C; c += 4) {
        f32x4 v = *reinterpret_cast<const f32x4*>(row + c);
        b += softplus_f(v.x);
        b += softplus_f(v.y);
        b += softplus_f(v.z);
        b += softplus_f(v.w);
    }
    base[n] = b;
}

__global__ void ce_direct(const float* __restrict__ pre, const float* __restrict__ base,
                          const int* __restrict__ idx, float* __restrict__ out, int N) {
    int m = blockIdx.x;
    int c = idx[m];
    int n0 = (blockIdx.y * blockDim.x + threadIdx.x) * 4;
    if (n0 >= N) return;
    f32x4 b = *reinterpret_cast<const f32x4*>(base + n0);
    f32x4 r;
    r.x = b.x - pre[(long)(n0 + 0) * CE_C + c];
    r.y = b.y - pre[(long)(n0 + 1) * CE_C + c];
    r.z = b.z - pre[(long)(n0 + 2) * CE_C + c];
    r.w = b.w - pre[(long)(n0 + 3) * CE_C + c];
    *reinterpret_cast<f32x4*>(out + (long)m * N + n0) = r;
}

extern "C" void kernel_launch(void* const* d_in, const int* in_sizes, int n_in,
                              void* d_out, int out_size, void* d_ws, size_t ws_size,
                              hipStream_t stream) {
    const int* idx   = (const int*)d_in[0];    // gt_kind_ind, int32 [M]
    const float* pre = (const float*)d_in[1];  // pre_cls, f32 [N, C]
    float* out = (float*)d_out;                // f32 [M, N]

    const int M = in_sizes[0];
    const int N = in_sizes[1] / CE_C;

    const size_t needD = (size_t)CE_C * (size_t)N * sizeof(float);

    if (ws_size >= needD) {
        float* D = (float*)d_ws;
        ce_prep<<<(N + 255) / 256, 256, 0, stream>>>(pre, D, N);
        if (N == 8192) {
            ce_gather_t<2048><<<M, 256, 0, stream>>>(
                reinterpret_cast<const f32x4*>(D), idx, reinterpret_cast<f32x4*>(out));
        } else {
            ce_gather<<<M, 256, 0, stream>>>(D, idx, out, N);
        }
    } else {
        float* base = (float*)d_ws;            // N floats
        ce_base<<<(N + 255) / 256, 256, 0, stream>>>(pre, base, N);
        dim3 grid(M, N / (4 * 256));
        ce_direct<<<grid, 256, 0, stream>>>(pre, base, idx, out, N);
    }
}